// Round 6
// baseline (1050.290 us; speedup 1.0000x reference)
//
#include <hip/hip_runtime.h>
#include <hip/hip_bf16.h>

typedef unsigned int u32;
typedef float f32x4 __attribute__((ext_vector_type(4)));

#define NGR 512     // graphs
#define NF 128      // edge features
#define GF 64       // global features
#define HID 64
#define IN1 192
#define NB 256      // one block per CU
#define EPB 6250    // E / NB  (E = 1,600,000)
#define TE2 512     // edges per tile
#define NTIL ((EPB + TE2 - 1) / TE2)   // 13

// Per CU: two column passes (f 0-63, f 64-127). LDS holds accum[512][64] f32
// (128 KB) + cnt[512]. Scatter-add via ds_add_f32; f-index XOR-swizzled by
// (seg&31) so same-f lanes with random segs spread across banks.
__launch_bounds__(1024, 1)
__global__ void stream_lds_kernel(const float* __restrict__ edge_attr,
                                  const int* __restrict__ ei0,
                                  const int* __restrict__ batch,
                                  float* __restrict__ partial,
                                  float* __restrict__ cntp) {
    extern __shared__ float accum[];              // [NGR*64] f32
    u32* cntsh = (u32*)(accum + NGR * 64);        // [NGR]

    const int tid = threadIdx.x;
    const int b = blockIdx.x;
    const int estart = b * EPB;
    const int eq = tid >> 2;        // edge slot within 256-group
    const int ql = tid & 3;         // quad lane (which 16B of the 64-f half)

    for (int pass = 0; pass < 2; ++pass) {
        for (int i = tid; i < NGR * 64; i += 1024) accum[i] = 0.0f;
        if (pass == 0 && tid < NGR) cntsh[tid] = 0u;
        __syncthreads();

        const int cb = pass * 64;   // column base (floats)

#pragma unroll 1
        for (int t = 0; t < NTIL; ++t) {
            const int ea = t * TE2 + eq;
            const int eb = ea + 256;
            const bool va = ea < EPB;
            const bool vb = eb < EPB;
            f32x4 ra[4], rb[4];
            int sa = 0, sb = 0;
            if (va) {
                const float* pa = edge_attr + (size_t)(estart + ea) * NF + cb + ql * 4;
#pragma unroll
                for (int j = 0; j < 4; ++j) ra[j] = *(const f32x4*)(pa + j * 16);
                sa = batch[ei0[estart + ea]];
            }
            if (vb) {
                const float* pb = edge_attr + (size_t)(estart + eb) * NF + cb + ql * 4;
#pragma unroll
                for (int j = 0; j < 4; ++j) rb[j] = *(const f32x4*)(pb + j * 16);
                sb = batch[ei0[estart + eb]];
            }
            if (va) {
                const int sw = sa & 31;
                float* rowp = accum + sa * 64;
#pragma unroll
                for (int j = 0; j < 4; ++j)
#pragma unroll
                    for (int c = 0; c < 4; ++c) {
                        const int f = (ql + 4 * j) * 4 + c;
                        atomicAdd(rowp + (f ^ sw), ra[j][c]);
                    }
                if (pass == 0 && ql == 0) atomicAdd(&cntsh[sa], 1u);
            }
            if (vb) {
                const int sw = sb & 31;
                float* rowp = accum + sb * 64;
#pragma unroll
                for (int j = 0; j < 4; ++j)
#pragma unroll
                    for (int c = 0; c < 4; ++c) {
                        const int f = (ql + 4 * j) * 4 + c;
                        atomicAdd(rowp + (f ^ sw), rb[j][c]);
                    }
                if (pass == 0 && ql == 0) atomicAdd(&cntsh[sb], 1u);
            }
        }
        __syncthreads();

        // flush this half to partial[b][g][cb .. cb+64)
#pragma unroll
        for (int k = 0; k < 8; ++k) {
            const int i = tid + k * 1024;
            const int g = i >> 4, q = i & 15;
            const int sw = g & 31;
            const float* rowp = accum + g * 64;
            float4 v;
            v.x = rowp[(q * 4 + 0) ^ sw];
            v.y = rowp[(q * 4 + 1) ^ sw];
            v.z = rowp[(q * 4 + 2) ^ sw];
            v.w = rowp[(q * 4 + 3) ^ sw];
            *(float4*)(partial + ((size_t)b * NGR + g) * NF + cb + q * 4) = v;
        }
        __syncthreads();   // protect accum before next pass re-zeroes
    }
    if (tid < NGR) cntp[(size_t)b * NGR + tid] = (float)cntsh[tid];
}

__global__ void final_kernel(const float* __restrict__ partial,
                             const float* __restrict__ cntp,
                             const float* __restrict__ u,
                             const float* __restrict__ W1,
                             const float* __restrict__ b1,
                             const float* __restrict__ W2,
                             const float* __restrict__ b2,
                             float* __restrict__ out) {
    __shared__ float vin[IN1];
    __shared__ float hv[HID];
    __shared__ f32x4 red[8][32];
    __shared__ float csh[256];
    const int g = blockIdx.x, t = threadIdx.x;   // 256 threads

    csh[t] = cntp[(size_t)t * NGR + g];

    const int chunk = t & 31, grp = t >> 5;
    f32x4 s = {0.f, 0.f, 0.f, 0.f};
#pragma unroll 4
    for (int k = 0; k < 32; ++k) {
        int slab = grp + k * 8;
        const float4 vv = *(const float4*)(partial + ((size_t)slab * NGR + g) * NF + chunk * 4);
        s[0] += vv.x; s[1] += vv.y; s[2] += vv.z; s[3] += vv.w;
    }
    red[grp][chunk] = s;
    __syncthreads();
    if (t < 128) csh[t] += csh[t + 128];
    __syncthreads();
    if (t < 64) csh[t] += csh[t + 64];
    __syncthreads();
    if (t < 32) csh[t] += csh[t + 32];
    __syncthreads();
    if (t < 16) csh[t] += csh[t + 16];
    __syncthreads();
    if (t < 8) csh[t] += csh[t + 8];
    __syncthreads();
    if (t < 4) csh[t] += csh[t + 4];
    __syncthreads();
    if (t < 2) csh[t] += csh[t + 2];
    __syncthreads();
    if (t < 1) csh[t] += csh[t + 1];
    __syncthreads();
    const float cnt = fmaxf(csh[0], 1.0f);
    const float inv = 1.0f / cnt;
    if (t < GF) vin[t] = u[g * GF + t];
    if (t < 32) {
        f32x4 m = red[0][t];
#pragma unroll
        for (int r = 1; r < 8; ++r) {
            f32x4 q = red[r][t];
            m[0] += q[0]; m[1] += q[1]; m[2] += q[2]; m[3] += q[3];
        }
        vin[GF + t * 4 + 0] = m[0] * inv;
        vin[GF + t * 4 + 1] = m[1] * inv;
        vin[GF + t * 4 + 2] = m[2] * inv;
        vin[GF + t * 4 + 3] = m[3] * inv;
    }
    __syncthreads();
    if (t < HID) {
        float a = b1[t];
#pragma unroll
        for (int k = 0; k < IN1; ++k) a += vin[k] * W1[k * HID + t];
        hv[t] = fmaxf(a, 0.0f);
    }
    __syncthreads();
    if (t < GF) {
        float a = b2[t];
#pragma unroll
        for (int k = 0; k < HID; ++k) a += hv[k] * W2[k * GF + t];
        out[g * GF + t] = a;
    }
}

extern "C" void kernel_launch(void* const* d_in, const int* in_sizes, int n_in,
                              void* d_out, int out_size, void* d_ws, size_t ws_size,
                              hipStream_t stream) {
    // inputs: 0:x(unused) 1:edge_index[2,E] 2:edge_attr[E,128] 3:u[512,64]
    //         4:batch[50000] 5:W1[192,64] 6:b1[64] 7:W2[64,64] 8:b2[64]
    const int*   ei        = (const int*)d_in[1];
    const float* edge_attr = (const float*)d_in[2];
    const float* u         = (const float*)d_in[3];
    const int*   batch     = (const int*)d_in[4];
    const float* W1        = (const float*)d_in[5];
    const float* b1        = (const float*)d_in[6];
    const float* W2        = (const float*)d_in[7];
    const float* b2        = (const float*)d_in[8];
    float*       out       = (float*)d_out;

    const int* ei0 = ei;   // row 0 of edge_index

    // workspace: partial[NB][NGR][NF] f32 (64 MB) | cntp[NB][NGR] f32 (512 KB)
    float* partial = (float*)d_ws;
    float* cntp    = partial + (size_t)NB * NGR * NF;

    const size_t lds_bytes = (size_t)NGR * 64 * sizeof(float) + NGR * sizeof(u32);
    stream_lds_kernel<<<NB, 1024, lds_bytes, stream>>>(edge_attr, ei0, batch,
                                                       partial, cntp);
    final_kernel<<<NGR, 256, 0, stream>>>(partial, cntp, u, W1, b1, W2, b2, out);
}

// Round 7
// 208.533 us; speedup vs baseline: 5.0366x; 5.0366x over previous
//
#include <hip/hip_runtime.h>
#include <hip/hip_bf16.h>

typedef unsigned int u32;
typedef unsigned short u16;
typedef float f32x4 __attribute__((ext_vector_type(4)));

#define NGR   512
#define NF    128
#define GF    64
#define HID   64
#define IN1   192
#define CHUNK 1024            // edges per reduce work-item
#define MAXIT 2600            // >= E/CHUNK + NGR = 2075 worst case

// hist/scatter tiling
#define HT    256
#define ITEMS 10
#define EPB   (HT * ITEMS)    // 2560

__global__ void zero_counts_kernel(u32* __restrict__ counts) {
    counts[threadIdx.x] = 0u;     // <<<1,512>>>
}

// Pass 1: seg[e] = batch[ei0[e]] (u16 cache) + global histogram.
__global__ void hist_kernel(const int* __restrict__ ei0,
                            const int* __restrict__ batch,
                            u32* __restrict__ g_counts,
                            u16* __restrict__ seg, int E) {
    __shared__ u32 h[NGR];
    int tid = threadIdx.x;
    h[tid] = 0u; h[tid + 256] = 0u;
    __syncthreads();
    int base = blockIdx.x * EPB + tid;
#pragma unroll
    for (int i = 0; i < ITEMS; ++i) {
        int e = base + i * HT;
        if (e < E) {
            int s = batch[ei0[e]];
            seg[e] = (u16)s;
            atomicAdd(&h[s], 1u);
        }
    }
    __syncthreads();
    u32 v0 = h[tid];       if (v0) atomicAdd(&g_counts[tid], v0);
    u32 v1 = h[tid + 256]; if (v1) atomicAdd(&g_counts[tid + 256], v1);
}

// Scan: offsets/cursor + balanced work-list of CHUNK-edge slices.
// work[i] = (g<<16)|slice ; item_start[g] = first item of graph g.
__global__ void scan_kernel(const u32* __restrict__ counts,
                            u32* __restrict__ offsets,
                            u32* __restrict__ cursor,
                            u32* __restrict__ work,
                            u32* __restrict__ item_start,
                            u32* __restrict__ header) {
    __shared__ u32 A[NGR], B[NGR];
    int t = threadIdx.x;                       // <<<1,512>>>
    u32 c = counts[t];
    // exclusive scan of counts
    A[t] = c;
    __syncthreads();
    u32 *src = A, *dst = B;
    for (int off = 1; off < NGR; off <<= 1) {
        u32 v = src[t];
        if (t >= off) v += src[t - off];
        dst[t] = v;
        __syncthreads();
        u32* tmp = src; src = dst; dst = tmp;
    }
    u32 exc = src[t] - c;
    offsets[t] = exc;
    cursor[t]  = exc;
    __syncthreads();
    // exclusive scan of slice counts
    u32 ns = (c + CHUNK - 1) / CHUNK;
    A[t] = ns;
    __syncthreads();
    src = A; dst = B;
    for (int off = 1; off < NGR; off <<= 1) {
        u32 v = src[t];
        if (t >= off) v += src[t - off];
        dst[t] = v;
        __syncthreads();
        u32* tmp = src; src = dst; dst = tmp;
    }
    u32 istart = src[t] - ns;
    item_start[t] = istart;
    if (t == NGR - 1) { item_start[NGR] = istart + ns; header[0] = istart + ns; }
    for (u32 s = 0; s < ns; ++s) work[istart + s] = ((u32)t << 16) | s;
}

__global__ void scatter_kernel(const u16* __restrict__ seg,
                               u32* __restrict__ cursor,
                               u32* __restrict__ sorted, int E) {
    __shared__ u32 h[NGR];
    __shared__ u32 bs[NGR];
    int tid = threadIdx.x;
    h[tid] = 0u; h[tid + 256] = 0u;
    __syncthreads();
    int base = blockIdx.x * EPB + tid;
    u16 segs[ITEMS];
    u16 ranks[ITEMS];
#pragma unroll
    for (int i = 0; i < ITEMS; ++i) {
        int e = base + i * HT;
        if (e < E) {
            int s = seg[e];
            segs[i]  = (u16)s;
            ranks[i] = (u16)atomicAdd(&h[s], 1u);
        }
    }
    __syncthreads();
    u32 v0 = h[tid];       if (v0) bs[tid]       = atomicAdd(&cursor[tid], v0);
    u32 v1 = h[tid + 256]; if (v1) bs[tid + 256] = atomicAdd(&cursor[tid + 256], v1);
    __syncthreads();
#pragma unroll
    for (int i = 0; i < ITEMS; ++i) {
        int e = base + i * HT;
        if (e < E) sorted[bs[segs[i]] + ranks[i]] = (u32)e;
    }
}

// Balanced gather-reduce: one work-item = up to CHUNK edges of one graph.
__launch_bounds__(256, 8)
__global__ void reduce_kernel(const float* __restrict__ edge_attr,
                              const u32* __restrict__ sorted,
                              const u32* __restrict__ counts,
                              const u32* __restrict__ offsets,
                              const u32* __restrict__ work,
                              const u32* __restrict__ header,
                              float* __restrict__ partial) {
    const u32 id = blockIdx.x;
    if (id >= header[0]) return;
    __shared__ float red[8 * NF];   // 4 KB

    const u32 w = work[id];
    const int g = (int)(w >> 16);
    const u32 sl = w & 0xFFFFu;
    const u32 off = offsets[g] + sl * CHUNK;
    const u32 len = min((u32)CHUNK, counts[g] - sl * CHUNK);

    const int tid = threadIdx.x;
    const int row = tid >> 5;     // 0..7
    const int lane = tid & 31;    // float4 slot in the 128-f row

    f32x4 a0 = {0.f,0.f,0.f,0.f}, a1 = a0, a2 = a0, a3 = a0;

    u32 j = (u32)row;
    for (; j + 24 < len; j += 32) {
        u32 e0 = sorted[off + j];
        u32 e1 = sorted[off + j + 8];
        u32 e2 = sorted[off + j + 16];
        u32 e3 = sorted[off + j + 24];
        f32x4 v0 = __builtin_nontemporal_load((const f32x4*)(edge_attr + (size_t)e0 * NF) + lane);
        f32x4 v1 = __builtin_nontemporal_load((const f32x4*)(edge_attr + (size_t)e1 * NF) + lane);
        f32x4 v2 = __builtin_nontemporal_load((const f32x4*)(edge_attr + (size_t)e2 * NF) + lane);
        f32x4 v3 = __builtin_nontemporal_load((const f32x4*)(edge_attr + (size_t)e3 * NF) + lane);
        a0 += v0; a1 += v1; a2 += v2; a3 += v3;
    }
    for (; j < len; j += 8) {
        u32 e = sorted[off + j];
        f32x4 v = __builtin_nontemporal_load((const f32x4*)(edge_attr + (size_t)e * NF) + lane);
        a0 += v;
    }
    a0 += a1 + a2 + a3;
    *(f32x4*)(red + row * NF + lane * 4) = a0;
    __syncthreads();

    if (tid < NF) {
        float s = 0.f;
#pragma unroll
        for (int r = 0; r < 8; ++r) s += red[r * NF + tid];
        partial[(size_t)id * NF + tid] = s;
    }
}

// Per graph: sum its work-item partials, mean, 2-layer MLP.
__global__ void final_kernel(const float* __restrict__ partial,
                             const u32* __restrict__ counts,
                             const u32* __restrict__ item_start,
                             const float* __restrict__ u,
                             const float* __restrict__ W1,
                             const float* __restrict__ b1,
                             const float* __restrict__ W2,
                             const float* __restrict__ b2,
                             float* __restrict__ out) {
    __shared__ float vin[IN1];
    __shared__ float hv[HID];
    const int g = blockIdx.x, t = threadIdx.x;   // 256 threads
    const u32 a = item_start[g], b = item_start[g + 1];
    if (t < NF) {
        float s = 0.f;
        for (u32 it = a; it < b; ++it) s += partial[(size_t)it * NF + t];
        vin[GF + t] = s / fmaxf((float)counts[g], 1.0f);
    }
    if (t >= NF && t < NF + GF) vin[t - NF] = u[g * GF + (t - NF)];
    __syncthreads();
    if (t < HID) {
        float acc = b1[t];
#pragma unroll
        for (int k = 0; k < IN1; ++k) acc += vin[k] * W1[k * HID + t];
        hv[t] = fmaxf(acc, 0.0f);
    }
    __syncthreads();
    if (t < GF) {
        float acc = b2[t];
#pragma unroll
        for (int k = 0; k < HID; ++k) acc += hv[k] * W2[k * GF + t];
        out[g * GF + t] = acc;
    }
}

extern "C" void kernel_launch(void* const* d_in, const int* in_sizes, int n_in,
                              void* d_out, int out_size, void* d_ws, size_t ws_size,
                              hipStream_t stream) {
    // inputs: 0:x(unused) 1:edge_index[2,E] 2:edge_attr[E,128] 3:u[512,64]
    //         4:batch[50000] 5:W1[192,64] 6:b1[64] 7:W2[64,64] 8:b2[64]
    const int*   ei        = (const int*)d_in[1];
    const float* edge_attr = (const float*)d_in[2];
    const float* u         = (const float*)d_in[3];
    const int*   batch     = (const int*)d_in[4];
    const float* W1        = (const float*)d_in[5];
    const float* b1        = (const float*)d_in[6];
    const float* W2        = (const float*)d_in[7];
    const float* b2        = (const float*)d_in[8];
    float*       out       = (float*)d_out;

    const int E = in_sizes[1] / 2;
    const int* ei0 = ei;   // row 0 of edge_index

    // ws: sorted[E] | partial[MAXIT*128] | counts | offsets | cursor |
    //     item_start[513] | header[16] | work[MAXIT] | seg[E] u16
    u32*   sorted     = (u32*)d_ws;
    float* partial    = (float*)(sorted + E);
    u32*   counts     = (u32*)(partial + (size_t)MAXIT * NF);
    u32*   offsets    = counts + NGR;
    u32*   cursor     = offsets + NGR;
    u32*   item_start = cursor + NGR;
    u32*   header     = item_start + NGR + 1;
    u32*   work       = header + 16;
    u16*   seg        = (u16*)(work + MAXIT);

    const int nblocks = (E + EPB - 1) / EPB;

    zero_counts_kernel<<<1, NGR, 0, stream>>>(counts);
    hist_kernel<<<nblocks, HT, 0, stream>>>(ei0, batch, counts, seg, E);
    scan_kernel<<<1, NGR, 0, stream>>>(counts, offsets, cursor, work, item_start, header);
    scatter_kernel<<<nblocks, HT, 0, stream>>>(seg, cursor, sorted, E);
    reduce_kernel<<<MAXIT, 256, 0, stream>>>(edge_attr, sorted, counts, offsets,
                                             work, header, partial);
    final_kernel<<<NGR, 256, 0, stream>>>(partial, counts, item_start,
                                          u, W1, b1, W2, b2, out);
}